// Round 8
// baseline (37.359 us; speedup 1.0000x reference)
//
#include <hip/hip_runtime.h>

// out[n,p] = sum_{k=0..7} X[n, p+k] * W[p*8 + k] + b[p],  X zero-padded past P.
// N=1024, P=20000, K=8, LF=1. fp32.
//
// Round-7 lesson: every variant (strided-W regs / LDS-W / coalesced-Wt / nt
// stores) lands 35-37us with VGPR=32..52 -> the compiler REMATERIALIZES the
// 32-float W block inside the row loop no matter what (its occupancy
// heuristic), so each row pays a W re-access: ~28 TB/s of L2 traffic (81% of
// L2 ceiling) in the Wt variant. Fix: launder wv/bv through an opaque empty
// asm ("+v") after loading -> compiler cannot reload them; W stays in VGPRs
// and the row loop is pure X-load + FMA + store.

constexpr int N  = 1024;
constexpr int P  = 20000;
constexpr int K  = 8;
constexpr int P4 = P / 4;              // 5000 column-groups of 4
constexpr int COLS_PADDED = 5120;      // pad to whole blocks
constexpr int NCHUNKS = 128;           // row-chunks
constexpr int ROWS = N / NCHUNKS;      // 8 rows per thread

typedef float float4n __attribute__((ext_vector_type(4)));  // native vec4

// ---- one-time W transpose: W[p][k] -> Wt[k][p] (640KB in d_ws) ----
__global__ __launch_bounds__(256)
void transpose_w(const float* __restrict__ W, float* __restrict__ Wt) {
    int p = blockIdx.x * blockDim.x + threadIdx.x;
    if (p >= P) return;
    float4 a = *reinterpret_cast<const float4*>(W + (size_t)p * K);
    float4 c = *reinterpret_cast<const float4*>(W + (size_t)p * K + 4);
    Wt[0 * P + p] = a.x; Wt[1 * P + p] = a.y;
    Wt[2 * P + p] = a.z; Wt[3 * P + p] = a.w;
    Wt[4 * P + p] = c.x; Wt[5 * P + p] = c.y;
    Wt[6 * P + p] = c.z; Wt[7 * P + p] = c.w;
}

__global__ __launch_bounds__(256, 4)
void local_linear_kernel(const float* __restrict__ X,
                         const float* __restrict__ Wt,
                         const float* __restrict__ b,
                         float* __restrict__ out) {
    const int tid   = blockIdx.x * blockDim.x + threadIdx.x;
    const int chunk = tid / COLS_PADDED;
    const int q     = tid - chunk * COLS_PADDED;
    if (q >= P4) return;                     // padding lanes
    const int p  = q * 4;
    const int n0 = chunk * ROWS;

    // W for my 4 columns: 8 coalesced float4 loads (lanes have consecutive p)
    float4n wv[8];
    #pragma unroll
    for (int k = 0; k < K; ++k)
        wv[k] = *reinterpret_cast<const float4n*>(Wt + (size_t)k * P + p);
    float4n bv = *reinterpret_cast<const float4n*>(b + p);

    // Launder: wv/bv now originate from an opaque asm. The compiler cannot
    // rematerialize (re-load) them inside the row loop -> they stay in VGPRs.
    asm volatile("" : "+v"(wv[0]), "+v"(wv[1]), "+v"(wv[2]), "+v"(wv[3]),
                      "+v"(wv[4]), "+v"(wv[5]), "+v"(wv[6]), "+v"(wv[7]),
                      "+v"(bv));

    const bool interior = (p + 12 <= P);

    #pragma unroll 2
    for (int r = 0; r < ROWS; ++r) {
        const float* xrow = X + (size_t)(n0 + r) * P;

        float xv[12];
        if (interior) {
            float4n a = *reinterpret_cast<const float4n*>(xrow + p);
            float4n c = *reinterpret_cast<const float4n*>(xrow + p + 4);
            float4n d = *reinterpret_cast<const float4n*>(xrow + p + 8);
            xv[0] = a.x; xv[1] = a.y; xv[2]  = a.z; xv[3]  = a.w;
            xv[4] = c.x; xv[5] = c.y; xv[6]  = c.z; xv[7]  = c.w;
            xv[8] = d.x; xv[9] = d.y; xv[10] = d.z; xv[11] = d.w;
        } else {
            #pragma unroll
            for (int i = 0; i < 12; ++i)
                xv[i] = (p + i < P) ? xrow[p + i] : 0.0f;   // matches jnp.pad
        }

        float r0 = bv.x, r1 = bv.y, r2 = bv.z, r3 = bv.w;
        #pragma unroll
        for (int k = 0; k < K; ++k) {
            r0 += xv[k + 0] * wv[k].x;
            r1 += xv[k + 1] * wv[k].y;
            r2 += xv[k + 2] * wv[k].z;
            r3 += xv[k + 3] * wv[k].w;
        }

        float4n o; o.x = r0; o.y = r1; o.z = r2; o.w = r3;
        // Streaming store: out is write-once.
        __builtin_nontemporal_store(
            o, reinterpret_cast<float4n*>(out + (size_t)(n0 + r) * P + p));
    }
}

extern "C" void kernel_launch(void* const* d_in, const int* in_sizes, int n_in,
                              void* d_out, int out_size, void* d_ws, size_t ws_size,
                              hipStream_t stream) {
    const float* X = (const float*)d_in[0];
    const float* W = (const float*)d_in[1];
    const float* b = (const float*)d_in[2];
    float* out = (float*)d_out;

    constexpr int total_threads = COLS_PADDED * NCHUNKS;  // 655,360
    constexpr int block = 256;
    constexpr int grid = total_threads / block;           // 2,560 blocks

    float* Wt = (float*)d_ws;                              // 640KB scratch
    transpose_w<<<(P + block - 1) / block, block, 0, stream>>>(W, Wt);
    local_linear_kernel<<<grid, block, 0, stream>>>(X, Wt, b, out);
}